// Round 4
// baseline (314.125 us; speedup 1.0000x reference)
//
#include <hip/hip_runtime.h>

#define TB_L 1024
#define TB_E 1024

typedef __attribute__((ext_vector_type(8))) short bf16x8;
typedef __attribute__((ext_vector_type(8))) unsigned short u16x8;
typedef __attribute__((ext_vector_type(4))) float floatx4;

#define AS1(p) ((const __attribute__((address_space(1))) void*)(p))
#define AS3(p) ((__attribute__((address_space(3))) void*)(p))

static __device__ __forceinline__ unsigned short f2bf(float x) {
  union { float f; unsigned u; } c; c.f = x;
  unsigned r = c.u + 0x7fff + ((c.u >> 16) & 1);
  return (unsigned short)(r >> 16);
}
static __device__ __forceinline__ float bf2f(unsigned short h) {
  union { unsigned u; float f; } c; c.u = ((unsigned)h) << 16;
  return c.f;
}
static __device__ __forceinline__ float gelu_f(float x) {
  const float c0 = 0.7978845608028654f;
  const float c1 = 0.044715f;
  float x3 = x * x * x;
  return 0.5f * x * (1.0f + tanhf(c0 * (x + c1 * x3)));
}

// swizzled LDS addressing for 64-row x 128-byte tiles (attention)
static __device__ __forceinline__ int swz(int row, int bytecol) {
  return row * 128 +
         ((((bytecol >> 4) ^ ((row + (row >> 3)) & 7)) << 4) | (bytecol & 15));
}

// RMS norm over E=1024, one block per row, bf16 output.
__global__ __launch_bounds__(256) void rms_kernel(const float* __restrict__ x,
                                                  const float* __restrict__ w,
                                                  unsigned short* __restrict__ out) {
  const int row = blockIdx.x;
  const int tid = threadIdx.x;
  const float4 v = *(const float4*)(x + (size_t)row * TB_E + tid * 4);
  float s = v.x * v.x + v.y * v.y + v.z * v.z + v.w * v.w;
#pragma unroll
  for (int off = 32; off > 0; off >>= 1) s += __shfl_down(s, off);
  __shared__ float red[4];
  if ((tid & 63) == 0) red[tid >> 6] = s;
  __syncthreads();
  const float tot = red[0] + red[1] + red[2] + red[3];
  const float scale = rsqrtf(tot * (1.0f / TB_E) + 1e-6f);
  const float4 wv = *(const float4*)(w + tid * 4);
  ushort4 o;
  o.x = f2bf(v.x * scale * wv.x);
  o.y = f2bf(v.y * scale * wv.y);
  o.z = f2bf(v.z * scale * wv.z);
  o.w = f2bf(v.w * scale * wv.w);
  *(ushort4*)(out + (size_t)row * TB_E + tid * 4) = o;
}

// Fused transpose+bf16 of all 4 weights: in K x N fp32 -> out N x K bf16.
// Flat grid of 64x64 tiles: [0,768) qkv_w, [768,1024) out_w, [1024,2048) w1,
// [2048,3072) w2.
__global__ __launch_bounds__(256) void transpose_all(
    const float* __restrict__ s0, const float* __restrict__ s1,
    const float* __restrict__ s2, const float* __restrict__ s3,
    unsigned short* __restrict__ d0, unsigned short* __restrict__ d1,
    unsigned short* __restrict__ d2, unsigned short* __restrict__ d3) {
  const int id = blockIdx.x;
  const float* in; unsigned short* out; int K, N, lid;
  if (id < 768)       { in = s0; out = d0; K = 1024; N = 3072; lid = id; }
  else if (id < 1024) { in = s1; out = d1; K = 1024; N = 1024; lid = id - 768; }
  else if (id < 2048) { in = s2; out = d2; K = 1024; N = 4096; lid = id - 1024; }
  else                { in = s3; out = d3; K = 4096; N = 1024; lid = id - 2048; }
  const int nx = N >> 6;
  const int n0 = (lid % nx) * 64, k0 = (lid / nx) * 64;
  __shared__ float t[64][65];
  const int tid = threadIdx.x;
#pragma unroll
  for (int rep = 0; rep < 4; ++rep) {
    const int r = rep * 16 + (tid >> 4);
    const int c = (tid & 15) * 4;
    const float4 v = *(const float4*)(in + (size_t)(k0 + r) * N + n0 + c);
    t[r][c] = v.x; t[r][c + 1] = v.y; t[r][c + 2] = v.z; t[r][c + 3] = v.w;
  }
  __syncthreads();
#pragma unroll
  for (int rep = 0; rep < 4; ++rep) {
    const int n = rep * 16 + (tid >> 4);
    const int k = (tid & 15) * 4;
    ushort4 o;
    o.x = f2bf(t[k + 0][n]);
    o.y = f2bf(t[k + 1][n]);
    o.z = f2bf(t[k + 2][n]);
    o.w = f2bf(t[k + 3][n]);
    *(ushort4*)(out + (size_t)(n0 + n) * K + k0 + k) = o;
  }
}

// bf16 MFMA GEMM: C = act(A@B + bias) [+ res]
// A: M x K bf16 row-major.  Bt: N x K bf16 (k-contiguous).
// LDS layout: 1KB chunks of (16 rows x 32 k) in exact lane order
// (chunk = strip*KC + khalf), staged via global_load_lds width=16.
template <int BM, int BN, int BK, int WM, int WN, bool GELU>
__global__ __launch_bounds__(256) void gemm_bf16(
    const unsigned short* __restrict__ A, const unsigned short* __restrict__ Bt,
    const float* __restrict__ bias, const float* __restrict__ res,
    float* __restrict__ Cf, unsigned short* __restrict__ Cb,
    int M, int N, int K) {
  constexpr int KC = BK / 32;
  constexpr int WCOLS = BN / WN;
  constexpr int MT = WM / 16;
  constexpr int NT = WN / 16;
  constexpr int ACH = (BM / 16) * KC;  // 1KB chunks per A k-step
  constexpr int BCH = (BN / 16) * KC;
  static_assert((BM / WM) * (BN / WN) == 4, "4 waves");
  static_assert(ACH % 4 == 0 && BCH % 4 == 0, "chunks divisible by waves");
  __shared__ __align__(16) unsigned short As[BM * BK];
  __shared__ __align__(16) unsigned short Bs[BN * BK];
  const int tid = threadIdx.x;
  const int wid = tid >> 6, lane = tid & 63;
  const int m0 = blockIdx.y * BM, n0 = blockIdx.x * BN;
  const int mbase = (wid / WCOLS) * WM, nbase = (wid % WCOLS) * WN;

  floatx4 acc[MT][NT];
#pragma unroll
  for (int i = 0; i < MT; ++i)
#pragma unroll
    for (int j = 0; j < NT; ++j) {
      floatx4 z = {0.f, 0.f, 0.f, 0.f};
      acc[i][j] = z;
    }

  const int srow = lane >> 2;       // row within 16-row strip
  const int scol = (lane & 3) * 8;  // k element offset within 32-k chunk
  const unsigned short* Ag = A + (size_t)m0 * K;
  const unsigned short* Bg = Bt + (size_t)n0 * K;
  const char* Ab = (const char*)As;
  const char* Bb = (const char*)Bs;
  const int fr = (lane & 15);
  const int fk = (lane >> 4) * 16;

  for (int k0 = 0; k0 < K; k0 += BK) {
    __syncthreads();
#pragma unroll
    for (int j = 0; j < ACH / 4; ++j) {
      const int ch = j * 4 + wid;
      const int strip = ch / KC, half = ch % KC;
      __builtin_amdgcn_global_load_lds(
          AS1(Ag + (size_t)(strip * 16 + srow) * K + k0 + half * 32 + scol),
          AS3((char*)As + ch * 1024), 16, 0, 0);
    }
#pragma unroll
    for (int j = 0; j < BCH / 4; ++j) {
      const int ch = j * 4 + wid;
      const int strip = ch / KC, half = ch % KC;
      __builtin_amdgcn_global_load_lds(
          AS1(Bg + (size_t)(strip * 16 + srow) * K + k0 + half * 32 + scol),
          AS3((char*)Bs + ch * 1024), 16, 0, 0);
    }
    __syncthreads();
#pragma unroll
    for (int g = 0; g < KC; ++g) {
      bf16x8 af[MT], bfr[NT];
#pragma unroll
      for (int i = 0; i < MT; ++i)
        af[i] = *(const bf16x8*)(Ab + ((mbase / 16 + i) * KC + g) * 1024 +
                                 fr * 64 + fk);
#pragma unroll
      for (int j = 0; j < NT; ++j)
        bfr[j] = *(const bf16x8*)(Bb + ((nbase / 16 + j) * KC + g) * 1024 +
                                  fr * 64 + fk);
#pragma unroll
      for (int i = 0; i < MT; ++i)
#pragma unroll
        for (int j = 0; j < NT; ++j)
          acc[i][j] = __builtin_amdgcn_mfma_f32_16x16x32_bf16(af[i], bfr[j],
                                                              acc[i][j], 0, 0, 0);
    }
  }

  const int mr = (lane >> 4) * 4;
  const int nc = lane & 15;
#pragma unroll
  for (int i = 0; i < MT; ++i)
#pragma unroll
    for (int j = 0; j < NT; ++j) {
      const int n = n0 + nbase + j * 16 + nc;
      const float bv = bias[n];
#pragma unroll
      for (int r = 0; r < 4; ++r) {
        const int m = m0 + mbase + i * 16 + mr + r;
        float v = acc[i][j][r] + bv;
        if (GELU) v = gelu_f(v);
        if (res) v += res[(size_t)m * N + n];
        if (Cf) Cf[(size_t)m * N + n] = v;
        if (Cb) Cb[(size_t)m * N + n] = f2bf(v);
      }
    }
}

// Cosformer causal linear attention, MFMA flash-style.
__global__ __launch_bounds__(256) void attn_mfma(const unsigned short* __restrict__ qkv,
                                                 unsigned short* __restrict__ out) {
  const int it = blockIdx.x;
  const int bh = blockIdx.y;
  const int b = bh >> 4, h = bh & 15;
  const int tid = threadIdx.x;
  const int w = tid >> 6, lane = tid & 63;
  const int qd = lane >> 4, ln = lane & 15;
  const int i0 = it * 64;
  __shared__ __align__(16) char sq[8192];
  __shared__ __align__(16) char sk[8192];
  __shared__ __align__(16) char svt[8192];
  __shared__ __align__(16) char ss[8192];
  const unsigned short* base = qkv + (size_t)b * (TB_L * 3072) + h * 64;
  const float PH = 1.5339807878856412e-3f;  // pi/2/1024

#pragma unroll
  for (int p = 0; p < 2; ++p) {
    const int flat = p * 256 + tid;
    const int r = flat >> 3, c = flat & 7;
    u16x8 v = *(const u16x8*)(base + (size_t)(i0 + r) * 3072 + c * 8);
#pragma unroll
    for (int z = 0; z < 8; ++z) v[z] = (v[z] & 0x8000) ? (unsigned short)0 : v[z];
    *(u16x8*)(sq + swz(r, c * 16)) = v;
  }
  __syncthreads();

  bf16x8 aq[2];
#pragma unroll
  for (int ks = 0; ks < 2; ++ks)
    aq[ks] = *(const bf16x8*)(sq + swz(w * 16 + ln, ks * 64 + qd * 16));

  float ci[4], si[4];
#pragma unroll
  for (int r = 0; r < 4; ++r)
    __sincosf(PH * (float)(i0 + w * 16 + qd * 4 + r), &si[r], &ci[r]);

  floatx4 acc_o[4], acc_n;
  {
    floatx4 z = {0.f, 0.f, 0.f, 0.f};
#pragma unroll
    for (int nt = 0; nt < 4; ++nt) acc_o[nt] = z;
    acc_n = z;
  }
  bf16x8 ones;
#pragma unroll
  for (int z = 0; z < 8; ++z) ones[z] = (short)0x3F80;

  for (int jt = 0; jt <= it; ++jt) {
    const int j0 = jt * 64;
    __syncthreads();
#pragma unroll
    for (int p = 0; p < 2; ++p) {
      const int flat = p * 256 + tid;
      const int r = flat >> 3, c = flat & 7;
      u16x8 kv = *(const u16x8*)(base + (size_t)(j0 + r) * 3072 + 1024 + c * 8);
#pragma unroll
      for (int z = 0; z < 8; ++z) kv[z] = (kv[z] & 0x8000) ? (unsigned short)0 : kv[z];
      *(u16x8*)(sk + swz(r, c * 16)) = kv;
      u16x8 vv = *(const u16x8*)(base + (size_t)(j0 + r) * 3072 + 2048 + c * 8);
#pragma unroll
      for (int z = 0; z < 8; ++z)
        *(unsigned short*)(svt + swz(c * 8 + z, r * 2)) = (unsigned short)vv[z];
    }
    __syncthreads();

    floatx4 s_acc[4];
    {
      floatx4 z = {0.f, 0.f, 0.f, 0.f};
#pragma unroll
      for (int nt = 0; nt < 4; ++nt) s_acc[nt] = z;
    }
#pragma unroll
    for (int ks = 0; ks < 2; ++ks)
#pragma unroll
      for (int nt = 0; nt < 4; ++nt) {
        const bf16x8 bk = *(const bf16x8*)(sk + swz(nt * 16 + ln, ks * 64 + qd * 16));
        s_acc[nt] = __builtin_amdgcn_mfma_f32_16x16x32_bf16(aq[ks], bk, s_acc[nt], 0, 0, 0);
      }

    float cj[4], sj[4];
#pragma unroll
    for (int nt = 0; nt < 4; ++nt)
      __sincosf(PH * (float)(j0 + nt * 16 + ln), &sj[nt], &cj[nt]);
    const bool diag = (jt == it);
    const int li = w * 16 + qd * 4;
#pragma unroll
    for (int nt = 0; nt < 4; ++nt) {
      const int jl = nt * 16 + ln;
#pragma unroll
      for (int r = 0; r < 4; ++r) {
        float val = s_acc[nt][r] * (ci[r] * cj[nt] + si[r] * sj[nt]);
        if (diag && jl > li + r) val = 0.f;
        *(unsigned short*)(ss + swz(li + r, jl * 2)) = f2bf(val);
      }
    }

#pragma unroll
    for (int ks = 0; ks < 2; ++ks) {
      const bf16x8 as = *(const bf16x8*)(ss + swz(w * 16 + ln, ks * 64 + qd * 16));
#pragma unroll
      for (int nt = 0; nt < 4; ++nt) {
        const bf16x8 bv = *(const bf16x8*)(svt + swz(nt * 16 + ln, ks * 64 + qd * 16));
        acc_o[nt] = __builtin_amdgcn_mfma_f32_16x16x32_bf16(as, bv, acc_o[nt], 0, 0, 0);
      }
      acc_n = __builtin_amdgcn_mfma_f32_16x16x32_bf16(as, ones, acc_n, 0, 0, 0);
    }
  }

#pragma unroll
  for (int r = 0; r < 4; ++r) {
    const float inv = 1.0f / (acc_n[r] + 1e-6f);
    unsigned short* op =
        out + (size_t)(b * TB_L + i0 + w * 16 + qd * 4 + r) * TB_E + h * 64;
#pragma unroll
    for (int nt = 0; nt < 4; ++nt) op[nt * 16 + ln] = f2bf(acc_o[nt][r] * inv);
  }
}

extern "C" void kernel_launch(void* const* d_in, const int* in_sizes, int n_in,
                              void* d_out, int out_size, void* d_ws, size_t ws_size,
                              hipStream_t stream) {
  const float* x     = (const float*)d_in[0];
  const float* qkv_w = (const float*)d_in[1];
  const float* qkv_b = (const float*)d_in[2];
  const float* out_w = (const float*)d_in[3];
  const float* out_b = (const float*)d_in[4];
  const float* n1w   = (const float*)d_in[5];
  const float* n2w   = (const float*)d_in[6];
  const float* w1    = (const float*)d_in[7];
  const float* b1    = (const float*)d_in[8];
  const float* w2    = (const float*)d_in[9];
  const float* b2    = (const float*)d_in[10];

  char* wsb = (char*)d_ws;
  unsigned short* qkvb  = (unsigned short*)wsb;          // 2048x3072 bf16 / g 2048x4096
  unsigned short* g     = (unsigned short*)wsb;
  unsigned short* xnb   = (unsigned short*)(wsb + 16777216);
  unsigned short* attnb = (unsigned short*)(wsb + 20971520);
  float*          h     = (float*)(wsb + 25165824);
  unsigned short* qkvwt = (unsigned short*)(wsb + 33554432);
  unsigned short* outwt = (unsigned short*)(wsb + 39845888);
  unsigned short* w1t   = (unsigned short*)(wsb + 41943040);
  unsigned short* w2t   = (unsigned short*)(wsb + 50331648);
  float* out = (float*)d_out;
  const int M = 2048;

  transpose_all<<<dim3(3072), 256, 0, stream>>>(qkv_w, out_w, w1, w2,
                                                qkvwt, outwt, w1t, w2t);

  rms_kernel<<<dim3(M), 256, 0, stream>>>(x, n1w, xnb);
  gemm_bf16<128, 128, 32, 64, 64, false><<<dim3(3072 / 128, M / 128), 256, 0, stream>>>(
      xnb, qkvwt, qkv_b, nullptr, nullptr, qkvb, M, 3072, 1024);
  attn_mfma<<<dim3(16, 32), 256, 0, stream>>>(qkvb, attnb);
  gemm_bf16<128, 64, 32, 64, 32, false><<<dim3(1024 / 64, M / 128), 256, 0, stream>>>(
      attnb, outwt, out_b, x, h, nullptr, M, 1024, 1024);
  rms_kernel<<<dim3(M), 256, 0, stream>>>(h, n2w, xnb);
  gemm_bf16<128, 128, 32, 64, 64, true><<<dim3(4096 / 128, M / 128), 256, 0, stream>>>(
      xnb, w1t, b1, nullptr, nullptr, g, M, 4096, 1024);
  gemm_bf16<128, 64, 64, 64, 32, false><<<dim3(1024 / 64, M / 128), 256, 0, stream>>>(
      g, w2t, b2, h, out, nullptr, M, 1024, 4096);
}

// Round 5
// 279.037 us; speedup vs baseline: 1.1257x; 1.1257x over previous
//
#include <hip/hip_runtime.h>

#define TB_L 1024
#define TB_E 1024

typedef __attribute__((ext_vector_type(8))) short bf16x8;
typedef __attribute__((ext_vector_type(8))) unsigned short u16x8;
typedef __attribute__((ext_vector_type(4))) float floatx4;

#define AS1(p) ((const __attribute__((address_space(1))) void*)(p))
#define AS3(p) ((__attribute__((address_space(3))) void*)(p))

static __device__ __forceinline__ unsigned short f2bf(float x) {
  union { float f; unsigned u; } c; c.f = x;
  unsigned r = c.u + 0x7fff + ((c.u >> 16) & 1);
  return (unsigned short)(r >> 16);
}
static __device__ __forceinline__ float gelu_f(float x) {
  const float c0 = 0.7978845608028654f;
  const float c1 = 0.044715f;
  float x3 = x * x * x;
  return 0.5f * x * (1.0f + tanhf(c0 * (x + c1 * x3)));
}

// swizzled LDS addressing for 64-row x 128-byte tiles (attention)
static __device__ __forceinline__ int swz(int row, int bytecol) {
  return row * 128 +
         ((((bytecol >> 4) ^ ((row + (row >> 3)) & 7)) << 4) | (bytecol & 15));
}

// RMS norm over E=1024, one block per row, bf16 output.
__global__ __launch_bounds__(256) void rms_kernel(const float* __restrict__ x,
                                                  const float* __restrict__ w,
                                                  unsigned short* __restrict__ out) {
  const int row = blockIdx.x;
  const int tid = threadIdx.x;
  const float4 v = *(const float4*)(x + (size_t)row * TB_E + tid * 4);
  float s = v.x * v.x + v.y * v.y + v.z * v.z + v.w * v.w;
#pragma unroll
  for (int off = 32; off > 0; off >>= 1) s += __shfl_down(s, off);
  __shared__ float red[4];
  if ((tid & 63) == 0) red[tid >> 6] = s;
  __syncthreads();
  const float tot = red[0] + red[1] + red[2] + red[3];
  const float scale = rsqrtf(tot * (1.0f / TB_E) + 1e-6f);
  const float4 wv = *(const float4*)(w + tid * 4);
  ushort4 o;
  o.x = f2bf(v.x * scale * wv.x);
  o.y = f2bf(v.y * scale * wv.y);
  o.z = f2bf(v.z * scale * wv.z);
  o.w = f2bf(v.w * scale * wv.w);
  *(ushort4*)(out + (size_t)row * TB_E + tid * 4) = o;
}

// Fused transpose+bf16 of all 4 weights: in K x N fp32 -> out N x K bf16.
__global__ __launch_bounds__(256) void transpose_all(
    const float* __restrict__ s0, const float* __restrict__ s1,
    const float* __restrict__ s2, const float* __restrict__ s3,
    unsigned short* __restrict__ d0, unsigned short* __restrict__ d1,
    unsigned short* __restrict__ d2, unsigned short* __restrict__ d3) {
  const int id = blockIdx.x;
  const float* in; unsigned short* out; int K, N, lid;
  if (id < 768)       { in = s0; out = d0; K = 1024; N = 3072; lid = id; }
  else if (id < 1024) { in = s1; out = d1; K = 1024; N = 1024; lid = id - 768; }
  else if (id < 2048) { in = s2; out = d2; K = 1024; N = 4096; lid = id - 1024; }
  else                { in = s3; out = d3; K = 4096; N = 1024; lid = id - 2048; }
  const int nx = N >> 6;
  const int n0 = (lid % nx) * 64, k0 = (lid / nx) * 64;
  __shared__ float t[64][65];
  const int tid = threadIdx.x;
#pragma unroll
  for (int rep = 0; rep < 4; ++rep) {
    const int r = rep * 16 + (tid >> 4);
    const int c = (tid & 15) * 4;
    const float4 v = *(const float4*)(in + (size_t)(k0 + r) * N + n0 + c);
    t[r][c] = v.x; t[r][c + 1] = v.y; t[r][c + 2] = v.z; t[r][c + 3] = v.w;
  }
  __syncthreads();
#pragma unroll
  for (int rep = 0; rep < 4; ++rep) {
    const int n = rep * 16 + (tid >> 4);
    const int k = (tid & 15) * 4;
    ushort4 o;
    o.x = f2bf(t[k + 0][n]);
    o.y = f2bf(t[k + 1][n]);
    o.z = f2bf(t[k + 2][n]);
    o.w = f2bf(t[k + 3][n]);
    *(ushort4*)(out + (size_t)(n0 + n) * K + k0 + k) = o;
  }
}

// bf16 MFMA GEMM, double-buffered LDS, BK=32.
// A: M x K bf16 row-major.  Bt: N x K bf16 (k-contiguous).
// If Cpart != null: raw fp32 partial to Cpart + blockIdx.z*M*N (split-K).
// LDS layout per buffer: 1KB chunks of (16 rows x 32 k) in exact lane order.
template <int BM, int BN, int WM, int WN, bool GELU>
__global__ __launch_bounds__(256) void gemm_bf16(
    const unsigned short* __restrict__ A, const unsigned short* __restrict__ Bt,
    const float* __restrict__ bias, const float* __restrict__ res,
    float* __restrict__ Cf, unsigned short* __restrict__ Cb,
    float* __restrict__ Cpart, int M, int N, int K, int Ksl) {
  constexpr int WCOLS = BN / WN;
  constexpr int MT = WM / 16;
  constexpr int NT = WN / 16;
  constexpr int ACH = BM / 16;  // 1KB chunks per k-step
  constexpr int BCH = BN / 16;
  static_assert((BM / WM) * (BN / WN) == 4, "4 waves");
  static_assert(ACH % 4 == 0 && BCH % 4 == 0, "chunks divisible by waves");
  __shared__ __align__(16) unsigned short As[2][BM * 32];
  __shared__ __align__(16) unsigned short Bs[2][BN * 32];
  const int tid = threadIdx.x;
  const int wid = tid >> 6, lane = tid & 63;
  const int m0 = blockIdx.y * BM, n0 = blockIdx.x * BN;
  const int k_off = blockIdx.z * Ksl;
  const int mbase = (wid / WCOLS) * WM, nbase = (wid % WCOLS) * WN;

  floatx4 acc[MT][NT];
#pragma unroll
  for (int i = 0; i < MT; ++i)
#pragma unroll
    for (int j = 0; j < NT; ++j) {
      floatx4 z = {0.f, 0.f, 0.f, 0.f};
      acc[i][j] = z;
    }

  const int srow = lane >> 2;       // row within 16-row strip
  const int scol = (lane & 3) * 8;  // k element offset
  const unsigned short* Ag = A + (size_t)m0 * K + k_off;
  const unsigned short* Bg = Bt + (size_t)n0 * K + k_off;
  const int fr = (lane & 15);
  const int fk = (lane >> 4) * 16;

  auto stage = [&](int buf, int k0) {
#pragma unroll
    for (int j = 0; j < ACH / 4; ++j) {
      const int ch = j * 4 + wid;
      __builtin_amdgcn_global_load_lds(
          AS1(Ag + (size_t)(ch * 16 + srow) * K + k0 + scol),
          AS3((char*)&As[buf][0] + ch * 1024), 16, 0, 0);
    }
#pragma unroll
    for (int j = 0; j < BCH / 4; ++j) {
      const int ch = j * 4 + wid;
      __builtin_amdgcn_global_load_lds(
          AS1(Bg + (size_t)(ch * 16 + srow) * K + k0 + scol),
          AS3((char*)&Bs[buf][0] + ch * 1024), 16, 0, 0);
    }
  };

  stage(0, 0);
  const int nsteps = Ksl / 32;
  for (int s = 0; s < nsteps; ++s) {
    __syncthreads();  // drains cur-buf loads; protects buf reuse
    const int cur = s & 1;
    if (s + 1 < nsteps) stage(cur ^ 1, (s + 1) * 32);
    const char* Ab = (const char*)&As[cur][0];
    const char* Bb = (const char*)&Bs[cur][0];
    bf16x8 af[MT], bfr[NT];
#pragma unroll
    for (int i = 0; i < MT; ++i)
      af[i] = *(const bf16x8*)(Ab + (mbase / 16 + i) * 1024 + fr * 64 + fk);
#pragma unroll
    for (int j = 0; j < NT; ++j)
      bfr[j] = *(const bf16x8*)(Bb + (nbase / 16 + j) * 1024 + fr * 64 + fk);
#pragma unroll
    for (int i = 0; i < MT; ++i)
#pragma unroll
      for (int j = 0; j < NT; ++j)
        acc[i][j] = __builtin_amdgcn_mfma_f32_16x16x32_bf16(af[i], bfr[j],
                                                            acc[i][j], 0, 0, 0);
  }

  const int mr = (lane >> 4) * 4;
  const int nc = lane & 15;
  float* P = Cpart ? (Cpart + (size_t)blockIdx.z * M * N) : nullptr;
#pragma unroll
  for (int i = 0; i < MT; ++i)
#pragma unroll
    for (int j = 0; j < NT; ++j) {
      const int n = n0 + nbase + j * 16 + nc;
      const float bv = bias ? bias[n] : 0.f;
#pragma unroll
      for (int r = 0; r < 4; ++r) {
        const int m = m0 + mbase + i * 16 + mr + r;
        float v = acc[i][j][r] + bv;
        if (GELU) v = gelu_f(v);
        if (res) v += res[(size_t)m * N + n];
        if (P) P[(size_t)m * N + n] = v;
        if (Cf) Cf[(size_t)m * N + n] = v;
        if (Cb) Cb[(size_t)m * N + n] = f2bf(v);
      }
    }
}

// out = P0 + P1 + b2[n] + h, N=1024, M=2048 (split-K reduce + epilogue)
__global__ __launch_bounds__(256) void reduce_out(const float* __restrict__ P,
                                                  const float* __restrict__ h,
                                                  const float* __restrict__ b2,
                                                  float* __restrict__ out) {
  const int idx = (blockIdx.x * 256 + threadIdx.x) * 4;
  const int n = idx & 1023;
  const float4 a = *(const float4*)(P + idx);
  const float4 b = *(const float4*)(P + 2097152 + idx);
  const float4 hh = *(const float4*)(h + idx);
  const float4 bb = *(const float4*)(b2 + n);
  float4 o;
  o.x = a.x + b.x + hh.x + bb.x;
  o.y = a.y + b.y + hh.y + bb.y;
  o.z = a.z + b.z + hh.z + bb.z;
  o.w = a.w + b.w + hh.w + bb.w;
  *(float4*)(out + idx) = o;
}

// Cosformer causal linear attention, MFMA flash-style.
__global__ __launch_bounds__(256) void attn_mfma(const unsigned short* __restrict__ qkv,
                                                 unsigned short* __restrict__ out) {
  const int it = blockIdx.x;
  const int bh = blockIdx.y;
  const int b = bh >> 4, h = bh & 15;
  const int tid = threadIdx.x;
  const int w = tid >> 6, lane = tid & 63;
  const int qd = lane >> 4, ln = lane & 15;
  const int i0 = it * 64;
  __shared__ __align__(16) char sq[8192];
  __shared__ __align__(16) char sk[8192];
  __shared__ __align__(16) char svt[8192];
  __shared__ __align__(16) char ss[8192];
  const unsigned short* base = qkv + (size_t)b * (TB_L * 3072) + h * 64;
  const float PH = 1.5339807878856412e-3f;  // pi/2/1024

#pragma unroll
  for (int p = 0; p < 2; ++p) {
    const int flat = p * 256 + tid;
    const int r = flat >> 3, c = flat & 7;
    u16x8 v = *(const u16x8*)(base + (size_t)(i0 + r) * 3072 + c * 8);
#pragma unroll
    for (int z = 0; z < 8; ++z) v[z] = (v[z] & 0x8000) ? (unsigned short)0 : v[z];
    *(u16x8*)(sq + swz(r, c * 16)) = v;
  }
  __syncthreads();

  bf16x8 aq[2];
#pragma unroll
  for (int ks = 0; ks < 2; ++ks)
    aq[ks] = *(const bf16x8*)(sq + swz(w * 16 + ln, ks * 64 + qd * 16));

  float ci[4], si[4];
#pragma unroll
  for (int r = 0; r < 4; ++r)
    __sincosf(PH * (float)(i0 + w * 16 + qd * 4 + r), &si[r], &ci[r]);

  floatx4 acc_o[4], acc_n;
  {
    floatx4 z = {0.f, 0.f, 0.f, 0.f};
#pragma unroll
    for (int nt = 0; nt < 4; ++nt) acc_o[nt] = z;
    acc_n = z;
  }
  bf16x8 ones;
#pragma unroll
  for (int z = 0; z < 8; ++z) ones[z] = (short)0x3F80;

  for (int jt = 0; jt <= it; ++jt) {
    const int j0 = jt * 64;
    __syncthreads();
#pragma unroll
    for (int p = 0; p < 2; ++p) {
      const int flat = p * 256 + tid;
      const int r = flat >> 3, c = flat & 7;
      u16x8 kv = *(const u16x8*)(base + (size_t)(j0 + r) * 3072 + 1024 + c * 8);
#pragma unroll
      for (int z = 0; z < 8; ++z) kv[z] = (kv[z] & 0x8000) ? (unsigned short)0 : kv[z];
      *(u16x8*)(sk + swz(r, c * 16)) = kv;
      u16x8 vv = *(const u16x8*)(base + (size_t)(j0 + r) * 3072 + 2048 + c * 8);
#pragma unroll
      for (int z = 0; z < 8; ++z)
        *(unsigned short*)(svt + swz(c * 8 + z, r * 2)) = (unsigned short)vv[z];
    }
    __syncthreads();

    floatx4 s_acc[4];
    {
      floatx4 z = {0.f, 0.f, 0.f, 0.f};
#pragma unroll
      for (int nt = 0; nt < 4; ++nt) s_acc[nt] = z;
    }
#pragma unroll
    for (int ks = 0; ks < 2; ++ks)
#pragma unroll
      for (int nt = 0; nt < 4; ++nt) {
        const bf16x8 bk = *(const bf16x8*)(sk + swz(nt * 16 + ln, ks * 64 + qd * 16));
        s_acc[nt] = __builtin_amdgcn_mfma_f32_16x16x32_bf16(aq[ks], bk, s_acc[nt], 0, 0, 0);
      }

    float cj[4], sj[4];
#pragma unroll
    for (int nt = 0; nt < 4; ++nt)
      __sincosf(PH * (float)(j0 + nt * 16 + ln), &sj[nt], &cj[nt]);
    const bool diag = (jt == it);
    const int li = w * 16 + qd * 4;
#pragma unroll
    for (int nt = 0; nt < 4; ++nt) {
      const int jl = nt * 16 + ln;
#pragma unroll
      for (int r = 0; r < 4; ++r) {
        float val = s_acc[nt][r] * (ci[r] * cj[nt] + si[r] * sj[nt]);
        if (diag && jl > li + r) val = 0.f;
        *(unsigned short*)(ss + swz(li + r, jl * 2)) = f2bf(val);
      }
    }

#pragma unroll
    for (int ks = 0; ks < 2; ++ks) {
      const bf16x8 as = *(const bf16x8*)(ss + swz(w * 16 + ln, ks * 64 + qd * 16));
#pragma unroll
      for (int nt = 0; nt < 4; ++nt) {
        const bf16x8 bv = *(const bf16x8*)(svt + swz(nt * 16 + ln, ks * 64 + qd * 16));
        acc_o[nt] = __builtin_amdgcn_mfma_f32_16x16x32_bf16(as, bv, acc_o[nt], 0, 0, 0);
      }
      acc_n = __builtin_amdgcn_mfma_f32_16x16x32_bf16(as, ones, acc_n, 0, 0, 0);
    }
  }

#pragma unroll
  for (int r = 0; r < 4; ++r) {
    const float inv = 1.0f / (acc_n[r] + 1e-6f);
    unsigned short* op =
        out + (size_t)(b * TB_L + i0 + w * 16 + qd * 4 + r) * TB_E + h * 64;
#pragma unroll
    for (int nt = 0; nt < 4; ++nt) op[nt * 16 + ln] = f2bf(acc_o[nt][r] * inv);
  }
}

extern "C" void kernel_launch(void* const* d_in, const int* in_sizes, int n_in,
                              void* d_out, int out_size, void* d_ws, size_t ws_size,
                              hipStream_t stream) {
  const float* x     = (const float*)d_in[0];
  const float* qkv_w = (const float*)d_in[1];
  const float* qkv_b = (const float*)d_in[2];
  const float* out_w = (const float*)d_in[3];
  const float* out_b = (const float*)d_in[4];
  const float* n1w   = (const float*)d_in[5];
  const float* n2w   = (const float*)d_in[6];
  const float* w1    = (const float*)d_in[7];
  const float* b1    = (const float*)d_in[8];
  const float* w2    = (const float*)d_in[9];
  const float* b2    = (const float*)d_in[10];

  char* wsb = (char*)d_ws;
  unsigned short* qkvb  = (unsigned short*)wsb;        // 2048x3072 bf16; later g
  unsigned short* g     = (unsigned short*)wsb;        // 2048x4096 bf16
  unsigned short* xnb   = (unsigned short*)(wsb + 16777216);
  unsigned short* attnb = (unsigned short*)(wsb + 20971520);
  float*          h     = (float*)(wsb + 25165824);
  unsigned short* qkvwt = (unsigned short*)(wsb + 33554432);
  unsigned short* outwt = (unsigned short*)(wsb + 39845888);
  unsigned short* w1t   = (unsigned short*)(wsb + 41943040);
  unsigned short* w2t   = (unsigned short*)(wsb + 50331648);
  // split-K partials (16.8 MB) reuse dead qkvwt/outwt/w1t region
  float*          Pk    = (float*)(wsb + 33554432);
  float* out = (float*)d_out;
  const int M = 2048;

  transpose_all<<<dim3(3072), 256, 0, stream>>>(qkv_w, out_w, w1, w2,
                                                qkvwt, outwt, w1t, w2t);

  rms_kernel<<<dim3(M), 256, 0, stream>>>(x, n1w, xnb);
  gemm_bf16<64, 128, 32, 64, false><<<dim3(24, 32), 256, 0, stream>>>(
      xnb, qkvwt, qkv_b, nullptr, nullptr, qkvb, nullptr, M, 3072, 1024, 1024);
  attn_mfma<<<dim3(16, 32), 256, 0, stream>>>(qkvb, attnb);
  gemm_bf16<64, 64, 32, 32, false><<<dim3(16, 32), 256, 0, stream>>>(
      attnb, outwt, out_b, x, h, nullptr, nullptr, M, 1024, 1024, 1024);
  rms_kernel<<<dim3(M), 256, 0, stream>>>(h, n2w, xnb);
  gemm_bf16<64, 128, 32, 64, true><<<dim3(32, 32), 256, 0, stream>>>(
      xnb, w1t, b1, nullptr, nullptr, g, nullptr, M, 4096, 1024, 1024);
  gemm_bf16<64, 64, 32, 32, false><<<dim3(16, 32, 2), 256, 0, stream>>>(
      g, w2t, nullptr, nullptr, nullptr, nullptr, Pk, M, 1024, 4096, 2048);
  reduce_out<<<dim3(2048), 256, 0, stream>>>(Pk, h, b2, out);
}

// Round 6
// 264.775 us; speedup vs baseline: 1.1864x; 1.0539x over previous
//
#include <hip/hip_runtime.h>

#define TB_L 1024
#define TB_E 1024

typedef __attribute__((ext_vector_type(8))) short bf16x8;
typedef __attribute__((ext_vector_type(8))) unsigned short u16x8;
typedef __attribute__((ext_vector_type(4))) float floatx4;

#define AS1(p) ((const __attribute__((address_space(1))) void*)(p))
#define AS3(p) ((__attribute__((address_space(3))) void*)(p))

static __device__ __forceinline__ unsigned short f2bf(float x) {
  union { float f; unsigned u; } c; c.f = x;
  unsigned r = c.u + 0x7fff + ((c.u >> 16) & 1);
  return (unsigned short)(r >> 16);
}
static __device__ __forceinline__ float gelu_f(float x) {
  const float c0 = 0.7978845608028654f;
  const float c1 = 0.044715f;
  float x3 = x * x * x;
  return 0.5f * x * (1.0f + tanhf(c0 * (x + c1 * x3)));
}

// swizzled LDS addressing for 64-row x 128-byte tiles (attention)
static __device__ __forceinline__ int swz(int row, int bytecol) {
  return row * 128 +
         ((((bytecol >> 4) ^ ((row + (row >> 3)) & 7)) << 4) | (bytecol & 15));
}

// RMS norm over E=1024, one block per row, bf16 output.
__global__ __launch_bounds__(256) void rms_kernel(const float* __restrict__ x,
                                                  const float* __restrict__ w,
                                                  unsigned short* __restrict__ out) {
  const int row = blockIdx.x;
  const int tid = threadIdx.x;
  const float4 v = *(const float4*)(x + (size_t)row * TB_E + tid * 4);
  float s = v.x * v.x + v.y * v.y + v.z * v.z + v.w * v.w;
#pragma unroll
  for (int off = 32; off > 0; off >>= 1) s += __shfl_down(s, off);
  __shared__ float red[4];
  if ((tid & 63) == 0) red[tid >> 6] = s;
  __syncthreads();
  const float tot = red[0] + red[1] + red[2] + red[3];
  const float scale = rsqrtf(tot * (1.0f / TB_E) + 1e-6f);
  const float4 wv = *(const float4*)(w + tid * 4);
  ushort4 o;
  o.x = f2bf(v.x * scale * wv.x);
  o.y = f2bf(v.y * scale * wv.y);
  o.z = f2bf(v.z * scale * wv.z);
  o.w = f2bf(v.w * scale * wv.w);
  *(ushort4*)(out + (size_t)row * TB_E + tid * 4) = o;
}

// Fused transpose+bf16 of all 4 weights: in K x N fp32 -> out N x K bf16.
__global__ __launch_bounds__(256) void transpose_all(
    const float* __restrict__ s0, const float* __restrict__ s1,
    const float* __restrict__ s2, const float* __restrict__ s3,
    unsigned short* __restrict__ d0, unsigned short* __restrict__ d1,
    unsigned short* __restrict__ d2, unsigned short* __restrict__ d3) {
  const int id = blockIdx.x;
  const float* in; unsigned short* out; int K, N, lid;
  if (id < 768)       { in = s0; out = d0; K = 1024; N = 3072; lid = id; }
  else if (id < 1024) { in = s1; out = d1; K = 1024; N = 1024; lid = id - 768; }
  else if (id < 2048) { in = s2; out = d2; K = 1024; N = 4096; lid = id - 1024; }
  else                { in = s3; out = d3; K = 4096; N = 1024; lid = id - 2048; }
  const int nx = N >> 6;
  const int n0 = (lid % nx) * 64, k0 = (lid / nx) * 64;
  __shared__ float t[64][65];
  const int tid = threadIdx.x;
#pragma unroll
  for (int rep = 0; rep < 4; ++rep) {
    const int r = rep * 16 + (tid >> 4);
    const int c = (tid & 15) * 4;
    const float4 v = *(const float4*)(in + (size_t)(k0 + r) * N + n0 + c);
    t[r][c] = v.x; t[r][c + 1] = v.y; t[r][c + 2] = v.z; t[r][c + 3] = v.w;
  }
  __syncthreads();
#pragma unroll
  for (int rep = 0; rep < 4; ++rep) {
    const int n = rep * 16 + (tid >> 4);
    const int k = (tid & 15) * 4;
    ushort4 o;
    o.x = f2bf(t[k + 0][n]);
    o.y = f2bf(t[k + 1][n]);
    o.z = f2bf(t[k + 2][n]);
    o.w = f2bf(t[k + 3][n]);
    *(ushort4*)(out + (size_t)(n0 + n) * K + k0 + k) = o;
  }
}

// bf16 MFMA GEMM, double-buffered LDS, templated BK / thread count.
// A: M x K bf16 row-major.  Bt: N x K bf16 (k-contiguous).
// If Cpart != null: raw fp32 partial to Cpart + blockIdx.z*M*N (split-K).
// LDS layout per buffer: 1KB chunks of (16 rows x 32 k) in exact lane order;
// chunk index = row_strip*KC + k_half.  G=4 block-group swizzle for L2.
template <int BM, int BN, int BK, int WM, int WN, int NTH, bool GELU>
__global__ __launch_bounds__(NTH) void gemm_bf16(
    const unsigned short* __restrict__ A, const unsigned short* __restrict__ Bt,
    const float* __restrict__ bias, const float* __restrict__ res,
    float* __restrict__ Cf, unsigned short* __restrict__ Cb,
    float* __restrict__ Cpart, int M, int N, int K, int Ksl) {
  constexpr int NW = NTH / 64;
  constexpr int KC = BK / 32;
  constexpr int WCOLS = BN / WN;
  constexpr int MT = WM / 16;
  constexpr int NT = WN / 16;
  constexpr int ACH = (BM / 16) * KC;
  constexpr int BCH = (BN / 16) * KC;
  static_assert((BM / WM) * (BN / WN) == NW, "wave grid");
  static_assert(ACH % NW == 0 && BCH % NW == 0, "chunks divisible by waves");
  __shared__ __align__(16) unsigned short As[2][BM * BK];
  __shared__ __align__(16) unsigned short Bs[2][BN * BK];
  const int tid = threadIdx.x;
  const int wid = tid >> 6, lane = tid & 63;

  // group swizzle: G consecutive flat ids share one bx (B tile)
  constexpr int G = 4;
  const int nbx = gridDim.x;
  const int flat = blockIdx.y * nbx + blockIdx.x;
  const int grp = flat / (G * nbx), rem = flat % (G * nbx);
  const int m0 = (grp * G + rem % G) * BM;
  const int n0 = (rem / G) * BN;

  const int k_off = blockIdx.z * Ksl;
  const int mbase = (wid / WCOLS) * WM, nbase = (wid % WCOLS) * WN;

  floatx4 acc[MT][NT];
#pragma unroll
  for (int i = 0; i < MT; ++i)
#pragma unroll
    for (int j = 0; j < NT; ++j) {
      floatx4 z = {0.f, 0.f, 0.f, 0.f};
      acc[i][j] = z;
    }

  const int srow = lane >> 2;       // row within 16-row strip
  const int scol = (lane & 3) * 8;  // k element offset within 32-k chunk
  const unsigned short* Ag = A + (size_t)m0 * K + k_off;
  const unsigned short* Bg = Bt + (size_t)n0 * K + k_off;
  const int fr = (lane & 15);
  const int fk = (lane >> 4) * 16;

  auto stage = [&](int buf, int k0) {
#pragma unroll
    for (int j = 0; j < ACH / NW; ++j) {
      const int ch = j * NW + wid;
      const int strip = ch / KC, half = ch % KC;
      __builtin_amdgcn_global_load_lds(
          AS1(Ag + (size_t)(strip * 16 + srow) * K + k0 + half * 32 + scol),
          AS3((char*)&As[buf][0] + ch * 1024), 16, 0, 0);
    }
#pragma unroll
    for (int j = 0; j < BCH / NW; ++j) {
      const int ch = j * NW + wid;
      const int strip = ch / KC, half = ch % KC;
      __builtin_amdgcn_global_load_lds(
          AS1(Bg + (size_t)(strip * 16 + srow) * K + k0 + half * 32 + scol),
          AS3((char*)&Bs[buf][0] + ch * 1024), 16, 0, 0);
    }
  };

  stage(0, 0);
  const int nsteps = Ksl / BK;
  for (int s = 0; s < nsteps; ++s) {
    __syncthreads();  // drains cur-buf loads; protects buf reuse
    const int cur = s & 1;
    if (s + 1 < nsteps) stage(cur ^ 1, (s + 1) * BK);
    const char* Ab = (const char*)&As[cur][0];
    const char* Bb = (const char*)&Bs[cur][0];
#pragma unroll
    for (int g = 0; g < KC; ++g) {
      bf16x8 af[MT], bfr[NT];
#pragma unroll
      for (int i = 0; i < MT; ++i)
        af[i] = *(const bf16x8*)(Ab + ((mbase / 16 + i) * KC + g) * 1024 +
                                 fr * 64 + fk);
#pragma unroll
      for (int j = 0; j < NT; ++j)
        bfr[j] = *(const bf16x8*)(Bb + ((nbase / 16 + j) * KC + g) * 1024 +
                                  fr * 64 + fk);
#pragma unroll
      for (int i = 0; i < MT; ++i)
#pragma unroll
        for (int j = 0; j < NT; ++j)
          acc[i][j] = __builtin_amdgcn_mfma_f32_16x16x32_bf16(af[i], bfr[j],
                                                              acc[i][j], 0, 0, 0);
    }
  }

  const int mr = (lane >> 4) * 4;
  const int nc = lane & 15;
  float* P = Cpart ? (Cpart + (size_t)blockIdx.z * M * N) : nullptr;
#pragma unroll
  for (int i = 0; i < MT; ++i)
#pragma unroll
    for (int j = 0; j < NT; ++j) {
      const int n = n0 + nbase + j * 16 + nc;
      const float bv = bias ? bias[n] : 0.f;
#pragma unroll
      for (int r = 0; r < 4; ++r) {
        const int m = m0 + mbase + i * 16 + mr + r;
        float v = acc[i][j][r] + bv;
        if (GELU) v = gelu_f(v);
        if (res) v += res[(size_t)m * N + n];
        if (P) P[(size_t)m * N + n] = v;
        if (Cf) Cf[(size_t)m * N + n] = v;
        if (Cb) Cb[(size_t)m * N + n] = f2bf(v);
      }
    }
}

// out = P0 + P1 + b2[n] + h, N=1024, M=2048 (split-K reduce + epilogue)
__global__ __launch_bounds__(256) void reduce_out(const float* __restrict__ P,
                                                  const float* __restrict__ h,
                                                  const float* __restrict__ b2,
                                                  float* __restrict__ out) {
  const int idx = (blockIdx.x * 256 + threadIdx.x) * 4;
  const int n = idx & 1023;
  const float4 a = *(const float4*)(P + idx);
  const float4 b = *(const float4*)(P + 2097152 + idx);
  const float4 hh = *(const float4*)(h + idx);
  const float4 bb = *(const float4*)(b2 + n);
  float4 o;
  o.x = a.x + b.x + hh.x + bb.x;
  o.y = a.y + b.y + hh.y + bb.y;
  o.z = a.z + b.z + hh.z + bb.z;
  o.w = a.w + b.w + hh.w + bb.w;
  *(float4*)(out + idx) = o;
}

// Cosformer causal linear attention, MFMA flash-style.
__global__ __launch_bounds__(256) void attn_mfma(const unsigned short* __restrict__ qkv,
                                                 unsigned short* __restrict__ out) {
  const int it = blockIdx.x;
  const int bh = blockIdx.y;
  const int b = bh >> 4, h = bh & 15;
  const int tid = threadIdx.x;
  const int w = tid >> 6, lane = tid & 63;
  const int qd = lane >> 4, ln = lane & 15;
  const int i0 = it * 64;
  __shared__ __align__(16) char sq[8192];
  __shared__ __align__(16) char sk[8192];
  __shared__ __align__(16) char svt[8192];
  __shared__ __align__(16) char ss[8192];
  const unsigned short* base = qkv + (size_t)b * (TB_L * 3072) + h * 64;
  const float PH = 1.5339807878856412e-3f;  // pi/2/1024

#pragma unroll
  for (int p = 0; p < 2; ++p) {
    const int flat = p * 256 + tid;
    const int r = flat >> 3, c = flat & 7;
    u16x8 v = *(const u16x8*)(base + (size_t)(i0 + r) * 3072 + c * 8);
#pragma unroll
    for (int z = 0; z < 8; ++z) v[z] = (v[z] & 0x8000) ? (unsigned short)0 : v[z];
    *(u16x8*)(sq + swz(r, c * 16)) = v;
  }
  __syncthreads();

  bf16x8 aq[2];
#pragma unroll
  for (int ks = 0; ks < 2; ++ks)
    aq[ks] = *(const bf16x8*)(sq + swz(w * 16 + ln, ks * 64 + qd * 16));

  float ci[4], si[4];
#pragma unroll
  for (int r = 0; r < 4; ++r)
    __sincosf(PH * (float)(i0 + w * 16 + qd * 4 + r), &si[r], &ci[r]);

  floatx4 acc_o[4], acc_n;
  {
    floatx4 z = {0.f, 0.f, 0.f, 0.f};
#pragma unroll
    for (int nt = 0; nt < 4; ++nt) acc_o[nt] = z;
    acc_n = z;
  }
  bf16x8 ones;
#pragma unroll
  for (int z = 0; z < 8; ++z) ones[z] = (short)0x3F80;

  for (int jt = 0; jt <= it; ++jt) {
    const int j0 = jt * 64;
    __syncthreads();
#pragma unroll
    for (int p = 0; p < 2; ++p) {
      const int flat = p * 256 + tid;
      const int r = flat >> 3, c = flat & 7;
      u16x8 kv = *(const u16x8*)(base + (size_t)(j0 + r) * 3072 + 1024 + c * 8);
#pragma unroll
      for (int z = 0; z < 8; ++z) kv[z] = (kv[z] & 0x8000) ? (unsigned short)0 : kv[z];
      *(u16x8*)(sk + swz(r, c * 16)) = kv;
      u16x8 vv = *(const u16x8*)(base + (size_t)(j0 + r) * 3072 + 2048 + c * 8);
#pragma unroll
      for (int z = 0; z < 8; ++z)
        *(unsigned short*)(svt + swz(c * 8 + z, r * 2)) = (unsigned short)vv[z];
    }
    __syncthreads();

    floatx4 s_acc[4];
    {
      floatx4 z = {0.f, 0.f, 0.f, 0.f};
#pragma unroll
      for (int nt = 0; nt < 4; ++nt) s_acc[nt] = z;
    }
#pragma unroll
    for (int ks = 0; ks < 2; ++ks)
#pragma unroll
      for (int nt = 0; nt < 4; ++nt) {
        const bf16x8 bk = *(const bf16x8*)(sk + swz(nt * 16 + ln, ks * 64 + qd * 16));
        s_acc[nt] = __builtin_amdgcn_mfma_f32_16x16x32_bf16(aq[ks], bk, s_acc[nt], 0, 0, 0);
      }

    float cj[4], sj[4];
#pragma unroll
    for (int nt = 0; nt < 4; ++nt)
      __sincosf(PH * (float)(j0 + nt * 16 + ln), &sj[nt], &cj[nt]);
    const bool diag = (jt == it);
    const int li = w * 16 + qd * 4;
#pragma unroll
    for (int nt = 0; nt < 4; ++nt) {
      const int jl = nt * 16 + ln;
#pragma unroll
      for (int r = 0; r < 4; ++r) {
        float val = s_acc[nt][r] * (ci[r] * cj[nt] + si[r] * sj[nt]);
        if (diag && jl > li + r) val = 0.f;
        *(unsigned short*)(ss + swz(li + r, jl * 2)) = f2bf(val);
      }
    }

#pragma unroll
    for (int ks = 0; ks < 2; ++ks) {
      const bf16x8 as = *(const bf16x8*)(ss + swz(w * 16 + ln, ks * 64 + qd * 16));
#pragma unroll
      for (int nt = 0; nt < 4; ++nt) {
        const bf16x8 bv = *(const bf16x8*)(svt + swz(nt * 16 + ln, ks * 64 + qd * 16));
        acc_o[nt] = __builtin_amdgcn_mfma_f32_16x16x32_bf16(as, bv, acc_o[nt], 0, 0, 0);
      }
      acc_n = __builtin_amdgcn_mfma_f32_16x16x32_bf16(as, ones, acc_n, 0, 0, 0);
    }
  }

#pragma unroll
  for (int r = 0; r < 4; ++r) {
    const float inv = 1.0f / (acc_n[r] + 1e-6f);
    unsigned short* op =
        out + (size_t)(b * TB_L + i0 + w * 16 + qd * 4 + r) * TB_E + h * 64;
#pragma unroll
    for (int nt = 0; nt < 4; ++nt) op[nt * 16 + ln] = f2bf(acc_o[nt][r] * inv);
  }
}

extern "C" void kernel_launch(void* const* d_in, const int* in_sizes, int n_in,
                              void* d_out, int out_size, void* d_ws, size_t ws_size,
                              hipStream_t stream) {
  const float* x     = (const float*)d_in[0];
  const float* qkv_w = (const float*)d_in[1];
  const float* qkv_b = (const float*)d_in[2];
  const float* out_w = (const float*)d_in[3];
  const float* out_b = (const float*)d_in[4];
  const float* n1w   = (const float*)d_in[5];
  const float* n2w   = (const float*)d_in[6];
  const float* w1    = (const float*)d_in[7];
  const float* b1    = (const float*)d_in[8];
  const float* w2    = (const float*)d_in[9];
  const float* b2    = (const float*)d_in[10];

  char* wsb = (char*)d_ws;
  unsigned short* qkvb  = (unsigned short*)wsb;        // 2048x3072 bf16; later g
  unsigned short* g     = (unsigned short*)wsb;        // 2048x4096 bf16
  unsigned short* xnb   = (unsigned short*)(wsb + 16777216);
  unsigned short* attnb = (unsigned short*)(wsb + 20971520);
  float*          h     = (float*)(wsb + 25165824);
  unsigned short* qkvwt = (unsigned short*)(wsb + 33554432);
  unsigned short* outwt = (unsigned short*)(wsb + 39845888);
  unsigned short* w1t   = (unsigned short*)(wsb + 41943040);
  unsigned short* w2t   = (unsigned short*)(wsb + 50331648);
  // split-K partials (16.8 MB) reuse dead qkvwt/outwt/w1t region (w2t still live)
  float*          Pk    = (float*)(wsb + 33554432);
  float* out = (float*)d_out;
  const int M = 2048;

  transpose_all<<<dim3(3072), 256, 0, stream>>>(qkv_w, out_w, w1, w2,
                                                qkvwt, outwt, w1t, w2t);

  rms_kernel<<<dim3(M), 256, 0, stream>>>(x, n1w, xnb);
  gemm_bf16<64, 128, 64, 32, 32, 512, false><<<dim3(24, 32), 512, 0, stream>>>(
      xnb, qkvwt, qkv_b, nullptr, nullptr, qkvb, nullptr, M, 3072, 1024, 1024);
  attn_mfma<<<dim3(16, 32), 256, 0, stream>>>(qkvb, attnb);
  gemm_bf16<64, 64, 64, 32, 32, 256, false><<<dim3(16, 32), 256, 0, stream>>>(
      attnb, outwt, out_b, x, h, nullptr, nullptr, M, 1024, 1024, 1024);
  rms_kernel<<<dim3(M), 256, 0, stream>>>(h, n2w, xnb);
  gemm_bf16<64, 128, 64, 32, 32, 512, true><<<dim3(32, 32), 512, 0, stream>>>(
      xnb, w1t, b1, nullptr, nullptr, g, nullptr, M, 4096, 1024, 1024);
  gemm_bf16<64, 128, 64, 32, 32, 512, false><<<dim3(8, 32, 2), 512, 0, stream>>>(
      g, w2t, nullptr, nullptr, nullptr, nullptr, Pk, M, 1024, 4096, 2048);
  reduce_out<<<dim3(2048), 256, 0, stream>>>(Pk, h, b2, out);
}

// Round 7
// 248.351 us; speedup vs baseline: 1.2648x; 1.0661x over previous
//
#include <hip/hip_runtime.h>

#define TB_L 1024
#define TB_E 1024

typedef __attribute__((ext_vector_type(8))) short bf16x8;
typedef __attribute__((ext_vector_type(8))) unsigned short u16x8;
typedef __attribute__((ext_vector_type(4))) float floatx4;

#define AS1(p) ((const __attribute__((address_space(1))) void*)(p))
#define AS3(p) ((__attribute__((address_space(3))) void*)(p))

static __device__ __forceinline__ unsigned short f2bf(float x) {
  union { float f; unsigned u; } c; c.f = x;
  unsigned r = c.u + 0x7fff + ((c.u >> 16) & 1);
  return (unsigned short)(r >> 16);
}
static __device__ __forceinline__ float gelu_f(float x) {
  const float c0 = 0.7978845608028654f;
  const float c1 = 0.044715f;
  float x3 = x * x * x;
  return 0.5f * x * (1.0f + tanhf(c0 * (x + c1 * x3)));
}

// swizzled LDS addressing for 64-row x 128-byte tiles: 16B chunk XOR row&7
static __device__ __forceinline__ int swz(int row, int bytecol) {
  return row * 128 + ((((bytecol >> 4) ^ (row & 7)) << 4) | (bytecol & 15));
}

// RMS norm over E=1024, one block per row, bf16 output.
__global__ __launch_bounds__(256) void rms_kernel(const float* __restrict__ x,
                                                  const float* __restrict__ w,
                                                  unsigned short* __restrict__ out) {
  const int row = blockIdx.x;
  const int tid = threadIdx.x;
  const float4 v = *(const float4*)(x + (size_t)row * TB_E + tid * 4);
  float s = v.x * v.x + v.y * v.y + v.z * v.z + v.w * v.w;
#pragma unroll
  for (int off = 32; off > 0; off >>= 1) s += __shfl_down(s, off);
  __shared__ float red[4];
  if ((tid & 63) == 0) red[tid >> 6] = s;
  __syncthreads();
  const float tot = red[0] + red[1] + red[2] + red[3];
  const float scale = rsqrtf(tot * (1.0f / TB_E) + 1e-6f);
  const float4 wv = *(const float4*)(w + tid * 4);
  ushort4 o;
  o.x = f2bf(v.x * scale * wv.x);
  o.y = f2bf(v.y * scale * wv.y);
  o.z = f2bf(v.z * scale * wv.z);
  o.w = f2bf(v.w * scale * wv.w);
  *(ushort4*)(out + (size_t)row * TB_E + tid * 4) = o;
}

// Fused transpose+bf16 of all 4 weights: in K x N fp32 -> out N x K bf16.
__global__ __launch_bounds__(256) void transpose_all(
    const float* __restrict__ s0, const float* __restrict__ s1,
    const float* __restrict__ s2, const float* __restrict__ s3,
    unsigned short* __restrict__ d0, unsigned short* __restrict__ d1,
    unsigned short* __restrict__ d2, unsigned short* __restrict__ d3) {
  const int id = blockIdx.x;
  const float* in; unsigned short* out; int K, N, lid;
  if (id < 768)       { in = s0; out = d0; K = 1024; N = 3072; lid = id; }
  else if (id < 1024) { in = s1; out = d1; K = 1024; N = 1024; lid = id - 768; }
  else if (id < 2048) { in = s2; out = d2; K = 1024; N = 4096; lid = id - 1024; }
  else                { in = s3; out = d3; K = 4096; N = 1024; lid = id - 2048; }
  const int nx = N >> 6;
  const int n0 = (lid % nx) * 64, k0 = (lid / nx) * 64;
  __shared__ float t[64][65];
  const int tid = threadIdx.x;
#pragma unroll
  for (int rep = 0; rep < 4; ++rep) {
    const int r = rep * 16 + (tid >> 4);
    const int c = (tid & 15) * 4;
    const float4 v = *(const float4*)(in + (size_t)(k0 + r) * N + n0 + c);
    t[r][c] = v.x; t[r][c + 1] = v.y; t[r][c + 2] = v.z; t[r][c + 3] = v.w;
  }
  __syncthreads();
#pragma unroll
  for (int rep = 0; rep < 4; ++rep) {
    const int n = rep * 16 + (tid >> 4);
    const int k = (tid & 15) * 4;
    ushort4 o;
    o.x = f2bf(t[k + 0][n]);
    o.y = f2bf(t[k + 1][n]);
    o.z = f2bf(t[k + 2][n]);
    o.w = f2bf(t[k + 3][n]);
    *(ushort4*)(out + (size_t)(n0 + n) * K + k0 + k) = o;
  }
}

// bf16 MFMA GEMM, double-buffered LDS.
// A: M x K bf16 row-major.  Bt: N x K bf16 (k-contiguous).
// relu_ncut: cols n < relu_ncut get relu (post-bias) -- used for q,k.
// VT: also scatter v-columns (n>=2048) transposed into vtp[bh][d][l] (qkv only).
// Cpart: raw fp32 partial to Cpart + blockIdx.z*M*N (split-K).
template <int BM, int BN, int BK, int WM, int WN, int NTH, bool GELU, bool VT>
__global__ __launch_bounds__(NTH) void gemm_bf16(
    const unsigned short* __restrict__ A, const unsigned short* __restrict__ Bt,
    const float* __restrict__ bias, const float* __restrict__ res,
    float* __restrict__ Cf, unsigned short* __restrict__ Cb,
    float* __restrict__ Cpart, unsigned short* __restrict__ vtp,
    int relu_ncut, int M, int N, int K, int Ksl) {
  constexpr int NW = NTH / 64;
  constexpr int KC = BK / 32;
  constexpr int WCOLS = BN / WN;
  constexpr int MT = WM / 16;
  constexpr int NT = WN / 16;
  constexpr int ACH = (BM / 16) * KC;
  constexpr int BCH = (BN / 16) * KC;
  static_assert((BM / WM) * (BN / WN) == NW, "wave grid");
  static_assert(ACH % NW == 0 && BCH % NW == 0, "chunks divisible by waves");
  __shared__ __align__(16) unsigned short As[2][BM * BK];
  __shared__ __align__(16) unsigned short Bs[2][BN * BK];
  const int tid = threadIdx.x;
  const int wid = tid >> 6, lane = tid & 63;

  constexpr int G = 4;
  const int nbx = gridDim.x;
  const int flat = blockIdx.y * nbx + blockIdx.x;
  const int grp = flat / (G * nbx), rem = flat % (G * nbx);
  const int m0 = (grp * G + rem % G) * BM;
  const int n0 = (rem / G) * BN;

  const int k_off = blockIdx.z * Ksl;
  const int mbase = (wid / WCOLS) * WM, nbase = (wid % WCOLS) * WN;

  floatx4 acc[MT][NT];
#pragma unroll
  for (int i = 0; i < MT; ++i)
#pragma unroll
    for (int j = 0; j < NT; ++j) {
      floatx4 z = {0.f, 0.f, 0.f, 0.f};
      acc[i][j] = z;
    }

  const int srow = lane >> 2;
  const int scol = (lane & 3) * 8;
  const unsigned short* Ag = A + (size_t)m0 * K + k_off;
  const unsigned short* Bg = Bt + (size_t)n0 * K + k_off;
  const int fr = (lane & 15);
  const int fk = (lane >> 4) * 16;

  auto stage = [&](int buf, int k0) {
#pragma unroll
    for (int j = 0; j < ACH / NW; ++j) {
      const int ch = j * NW + wid;
      const int strip = ch / KC, half = ch % KC;
      __builtin_amdgcn_global_load_lds(
          AS1(Ag + (size_t)(strip * 16 + srow) * K + k0 + half * 32 + scol),
          AS3((char*)&As[buf][0] + ch * 1024), 16, 0, 0);
    }
#pragma unroll
    for (int j = 0; j < BCH / NW; ++j) {
      const int ch = j * NW + wid;
      const int strip = ch / KC, half = ch % KC;
      __builtin_amdgcn_global_load_lds(
          AS1(Bg + (size_t)(strip * 16 + srow) * K + k0 + half * 32 + scol),
          AS3((char*)&Bs[buf][0] + ch * 1024), 16, 0, 0);
    }
  };

  stage(0, 0);
  const int nsteps = Ksl / BK;
  for (int s = 0; s < nsteps; ++s) {
    __syncthreads();
    const int cur = s & 1;
    if (s + 1 < nsteps) stage(cur ^ 1, (s + 1) * BK);
    const char* Ab = (const char*)&As[cur][0];
    const char* Bb = (const char*)&Bs[cur][0];
#pragma unroll
    for (int g = 0; g < KC; ++g) {
      bf16x8 af[MT], bfr[NT];
#pragma unroll
      for (int i = 0; i < MT; ++i)
        af[i] = *(const bf16x8*)(Ab + ((mbase / 16 + i) * KC + g) * 1024 +
                                 fr * 64 + fk);
#pragma unroll
      for (int j = 0; j < NT; ++j)
        bfr[j] = *(const bf16x8*)(Bb + ((nbase / 16 + j) * KC + g) * 1024 +
                                  fr * 64 + fk);
#pragma unroll
      for (int i = 0; i < MT; ++i)
#pragma unroll
        for (int j = 0; j < NT; ++j)
          acc[i][j] = __builtin_amdgcn_mfma_f32_16x16x32_bf16(af[i], bfr[j],
                                                              acc[i][j], 0, 0, 0);
    }
  }

  const int mr = (lane >> 4) * 4;
  const int nc = lane & 15;
  float* P = Cpart ? (Cpart + (size_t)blockIdx.z * M * N) : nullptr;
#pragma unroll
  for (int i = 0; i < MT; ++i)
#pragma unroll
    for (int j = 0; j < NT; ++j) {
      const int n = n0 + nbase + j * 16 + nc;
      const float bv = bias ? bias[n] : 0.f;
      float tv[4];
#pragma unroll
      for (int r = 0; r < 4; ++r) {
        const int m = m0 + mbase + i * 16 + mr + r;
        float v = acc[i][j][r] + bv;
        if (GELU) v = gelu_f(v);
        if (n < relu_ncut) v = fmaxf(v, 0.f);
        if (res) v += res[(size_t)m * N + n];
        if (P) P[(size_t)m * N + n] = v;
        if (Cf) Cf[(size_t)m * N + n] = v;
        if (Cb) Cb[(size_t)m * N + n] = f2bf(v);
        tv[r] = v;
      }
      if (VT && n >= 2048) {
        const int mm = m0 + mbase + i * 16 + mr;
        const int bb = mm >> 10, l = mm & 1023;
        const int hh = (n - 2048) >> 6, dd = (n - 2048) & 63;
        ushort4 o;
        o.x = f2bf(tv[0]); o.y = f2bf(tv[1]);
        o.z = f2bf(tv[2]); o.w = f2bf(tv[3]);
        *(ushort4*)(vtp + (size_t)(bb * 16 + hh) * 65536 + dd * 1024 + l) = o;
      }
    }
}

// out = P0 + P1 + b2[n] + h, N=1024, M=2048 (split-K reduce + epilogue)
__global__ __launch_bounds__(256) void reduce_out(const float* __restrict__ P,
                                                  const float* __restrict__ h,
                                                  const float* __restrict__ b2,
                                                  float* __restrict__ out) {
  const int idx = (blockIdx.x * 256 + threadIdx.x) * 4;
  const int n = idx & 1023;
  const float4 a = *(const float4*)(P + idx);
  const float4 b = *(const float4*)(P + 2097152 + idx);
  const float4 hh = *(const float4*)(h + idx);
  const float4 bb = *(const float4*)(b2 + n);
  float4 o;
  o.x = a.x + b.x + hh.x + bb.x;
  o.y = a.y + b.y + hh.y + bb.y;
  o.z = a.z + b.z + hh.z + bb.z;
  o.w = a.w + b.w + hh.w + bb.w;
  *(float4*)(out + idx) = o;
}

// Cosformer causal linear attention, MFMA flash-style, async-staged.
// qkv holds relu'd q,k (done in qkv-GEMM epilogue); vt = V^T [bh][d][l].
// Block: one 64-row i-tile of one (b,h); grid (bh, it).
__global__ __launch_bounds__(256) void attn_mfma(
    const unsigned short* __restrict__ qkv,
    const unsigned short* __restrict__ vt,
    unsigned short* __restrict__ out) {
  const int bh = blockIdx.x;
  const int it = blockIdx.y;
  const int b = bh >> 4, h = bh & 15;
  const int tid = threadIdx.x;
  const int w = tid >> 6, lane = tid & 63;
  const int qd = lane >> 4, ln = lane & 15;
  const int i0 = it * 64;
  __shared__ __align__(16) char sq[8192];
  __shared__ __align__(16) char sk[2][8192];
  __shared__ __align__(16) char sv[2][8192];
  __shared__ __align__(16) char ss[8192];
  const unsigned short* qbase = qkv + (size_t)b * (TB_L * 3072) + h * 64;
  const unsigned short* kbase = qbase + 1024;
  const unsigned short* vbase = vt + (size_t)bh * 65536;
  const float PH = 1.5339807878856412e-3f;  // pi/2/1024

  const int sr = lane >> 3;              // row within 8-row strip
  const int cg = ((lane & 7) ^ sr) * 8;  // swizzled source chunk (elements)

  // stage Q' (already relu'd): 8 chunks over 4 waves
#pragma unroll
  for (int p = 0; p < 2; ++p) {
    const int ch = p * 4 + w;
    __builtin_amdgcn_global_load_lds(
        AS1(qbase + (size_t)(i0 + ch * 8 + sr) * 3072 + cg),
        AS3(sq + ch * 1024), 16, 0, 0);
  }
  auto stage_kv = [&](int buf, int jt) {
    const int j0 = jt * 64;
#pragma unroll
    for (int p = 0; p < 4; ++p) {
      const int ch = p * 4 + w;
      if (ch < 8) {
        __builtin_amdgcn_global_load_lds(
            AS1(kbase + (size_t)(j0 + ch * 8 + sr) * 3072 + cg),
            AS3(sk[buf] + ch * 1024), 16, 0, 0);
      } else {
        __builtin_amdgcn_global_load_lds(
            AS1(vbase + (size_t)((ch - 8) * 8 + sr) * 1024 + j0 + cg),
            AS3(sv[buf] + (ch - 8) * 1024), 16, 0, 0);
      }
    }
  };
  stage_kv(0, 0);
  __syncthreads();

  bf16x8 aq[2];
#pragma unroll
  for (int ks = 0; ks < 2; ++ks)
    aq[ks] = *(const bf16x8*)(sq + swz(w * 16 + ln, ks * 64 + qd * 16));

  float ci[4], si[4];
#pragma unroll
  for (int r = 0; r < 4; ++r)
    __sincosf(PH * (float)(i0 + w * 16 + qd * 4 + r), &si[r], &ci[r]);

  floatx4 acc_o[4], acc_n;
  {
    floatx4 z = {0.f, 0.f, 0.f, 0.f};
#pragma unroll
    for (int nt = 0; nt < 4; ++nt) acc_o[nt] = z;
    acc_n = z;
  }
  bf16x8 ones;
#pragma unroll
  for (int z = 0; z < 8; ++z) ones[z] = (short)0x3F80;  // bf16 1.0

  for (int jt = 0; jt <= it; ++jt) {
    const int cur = jt & 1;
    if (jt < it) stage_kv(cur ^ 1, jt + 1);  // async prefetch next tile
    const char* skb = sk[cur];
    const char* svb = sv[cur];
    const int j0 = jt * 64;

    // S = Q'K'^T (16 rows x 64 j per wave)
    floatx4 s_acc[4];
    {
      floatx4 z = {0.f, 0.f, 0.f, 0.f};
#pragma unroll
      for (int nt = 0; nt < 4; ++nt) s_acc[nt] = z;
    }
#pragma unroll
    for (int ks = 0; ks < 2; ++ks)
#pragma unroll
      for (int nt = 0; nt < 4; ++nt) {
        const bf16x8 bk =
            *(const bf16x8*)(skb + swz(nt * 16 + ln, ks * 64 + qd * 16));
        s_acc[nt] =
            __builtin_amdgcn_mfma_f32_16x16x32_bf16(aq[ks], bk, s_acc[nt], 0, 0, 0);
      }

    // cos weighting (exact fp32: cos(ti-tj)=ci*cj+si*sj), causal mask, to LDS
    float cj[4], sj[4];
#pragma unroll
    for (int nt = 0; nt < 4; ++nt)
      __sincosf(PH * (float)(j0 + nt * 16 + ln), &sj[nt], &cj[nt]);
    const bool diag = (jt == it);
    const int li = w * 16 + qd * 4;
#pragma unroll
    for (int nt = 0; nt < 4; ++nt) {
      const int jl = nt * 16 + ln;
#pragma unroll
      for (int r = 0; r < 4; ++r) {
        float val = s_acc[nt][r] * (ci[r] * cj[nt] + si[r] * sj[nt]);
        if (diag && jl > li + r) val = 0.f;
        *(unsigned short*)(ss + swz(li + r, jl * 2)) = f2bf(val);
      }
    }

    // PV + norm (wave reads only its own ss rows)
#pragma unroll
    for (int ks = 0; ks < 2; ++ks) {
      const bf16x8 as = *(const bf16x8*)(ss + swz(w * 16 + ln, ks * 64 + qd * 16));
#pragma unroll
      for (int nt = 0; nt < 4; ++nt) {
        const bf16x8 bv =
            *(const bf16x8*)(svb + swz(nt * 16 + ln, ks * 64 + qd * 16));
        acc_o[nt] =
            __builtin_amdgcn_mfma_f32_16x16x32_bf16(as, bv, acc_o[nt], 0, 0, 0);
      }
      acc_n = __builtin_amdgcn_mfma_f32_16x16x32_bf16(as, ones, acc_n, 0, 0, 0);
    }
    __syncthreads();  // drains prefetch; all waves done with cur buffer
  }

#pragma unroll
  for (int r = 0; r < 4; ++r) {
    const float inv = 1.0f / (acc_n[r] + 1e-6f);
    unsigned short* op =
        out + (size_t)(b * TB_L + i0 + w * 16 + qd * 4 + r) * TB_E + h * 64;
#pragma unroll
    for (int nt = 0; nt < 4; ++nt) op[nt * 16 + ln] = f2bf(acc_o[nt][r] * inv);
  }
}

extern "C" void kernel_launch(void* const* d_in, const int* in_sizes, int n_in,
                              void* d_out, int out_size, void* d_ws, size_t ws_size,
                              hipStream_t stream) {
  const float* x     = (const float*)d_in[0];
  const float* qkv_w = (const float*)d_in[1];
  const float* qkv_b = (const float*)d_in[2];
  const float* out_w = (const float*)d_in[3];
  const float* out_b = (const float*)d_in[4];
  const float* n1w   = (const float*)d_in[5];
  const float* n2w   = (const float*)d_in[6];
  const float* w1    = (const float*)d_in[7];
  const float* b1    = (const float*)d_in[8];
  const float* w2    = (const float*)d_in[9];
  const float* b2    = (const float*)d_in[10];

  char* wsb = (char*)d_ws;
  unsigned short* qkvb  = (unsigned short*)wsb;             // 2048x3072 bf16
  unsigned short* g     = (unsigned short*)wsb;             // later: 2048x4096 bf16
  unsigned short* vt    = (unsigned short*)(wsb + 12582912); // 32x64x1024 bf16 (4MB)
  unsigned short* xnb   = (unsigned short*)(wsb + 16777216);
  unsigned short* attnb = (unsigned short*)(wsb + 20971520);
  float*          h     = (float*)(wsb + 25165824);
  unsigned short* qkvwt = (unsigned short*)(wsb + 33554432);
  unsigned short* outwt = (unsigned short*)(wsb + 39845888);
  unsigned short* w1t   = (unsigned short*)(wsb + 41943040);
  unsigned short* w2t   = (unsigned short*)(wsb + 50331648);
  float*          Pk    = (float*)(wsb + 33554432);  // reuses dead qkvwt/outwt
  float* out = (float*)d_out;
  const int M = 2048;

  transpose_all<<<dim3(3072), 256, 0, stream>>>(qkv_w, out_w, w1, w2,
                                                qkvwt, outwt, w1t, w2t);

  rms_kernel<<<dim3(M), 256, 0, stream>>>(x, n1w, xnb);
  // qkv: relu'd q,k in-place; v also transposed into vt
  gemm_bf16<64, 128, 64, 32, 32, 512, false, true><<<dim3(24, 32), 512, 0, stream>>>(
      xnb, qkvwt, qkv_b, nullptr, nullptr, qkvb, nullptr, vt, 2048, M, 3072, 1024, 1024);
  attn_mfma<<<dim3(32, 16), 256, 0, stream>>>(qkvb, vt, attnb);
  gemm_bf16<64, 64, 64, 32, 32, 256, false, false><<<dim3(16, 32), 256, 0, stream>>>(
      attnb, outwt, out_b, x, h, nullptr, nullptr, nullptr, 0, M, 1024, 1024, 1024);
  rms_kernel<<<dim3(M), 256, 0, stream>>>(h, n2w, xnb);
  gemm_bf16<64, 128, 64, 32, 32, 512, true, false><<<dim3(32, 32), 512, 0, stream>>>(
      xnb, w1t, b1, nullptr, nullptr, g, nullptr, nullptr, 0, M, 4096, 1024, 1024);
  gemm_bf16<64, 128, 64, 32, 32, 512, false, false><<<dim3(8, 32, 2), 512, 0, stream>>>(
      g, w2t, nullptr, nullptr, nullptr, nullptr, Pk, nullptr, 0, M, 1024, 4096, 2048);
  reduce_out<<<dim3(2048), 256, 0, stream>>>(Pk, h, b2, out);
}